// Round 7
// baseline (77.758 us; speedup 1.0000x reference)
//
#include <hip/hip_runtime.h>
#include <math.h>

// CapsuleLinear routing — MFMA formulation, round 7.
// logits = Xb @ Y (K=8 pad 32) and S_aug = P^T @ [Xb | 1] via
// __builtin_amdgcn_mfma_f32_16x16x32_bf16 (layouts verified in R6:
// A[m=lane&15][k=quad*8+j], C/D[col=lane&15][row=quad*4+reg]).
// Grid 512 = 64 b x 8 og (8 capsules each), T=256 (4 waves), 18 n-tiles/wave.
// LDS ~67.5 KB -> 2 blocks/CU so barriers/epilogues overlap across blocks.
// it0 folded into prologue (fp32 column sums). Probs via LDS stash -> coalesced.

#define NCAPS 1152
#define ILEN  8
#define OCAPS 64
#define OLEN  16
#define T     256
#define NWAVE 4
#define TPW   18         // n-tiles of 16 per wave (72 total)
#define NITER 3
#define OG    8
#define XT_PITCH 1156    // ushorts per xaugT row (2312 B, 8B-aligned, bank stride 578%32=2)
#define E_PITCH  1160    // ushorts per eL row (2320 B, 8B-aligned, bank stride 580%32=4)

typedef __attribute__((ext_vector_type(8))) short short8;
typedef __attribute__((ext_vector_type(4))) float f32x4;

__device__ __forceinline__ unsigned f2bf_u(float f) {   // RNE float->bf16 bits
    unsigned u = __builtin_bit_cast(unsigned, f);
    return (u + 0x7FFFu + ((u >> 16) & 1u)) >> 16;
}
__device__ __forceinline__ unsigned pack2(float a, float b) {
    return f2bf_u(a) | (f2bf_u(b) << 16);
}
__device__ __forceinline__ float bf2f(unsigned h) {
    return __builtin_bit_cast(float, h << 16);
}
__device__ __forceinline__ short8 s8_from(unsigned a, unsigned b, unsigned c, unsigned d) {
    uint4 t = make_uint4(a, b, c, d);
    return __builtin_bit_cast(short8, t);
}

template<int CTRL>
__device__ __forceinline__ float dpp_add(float x) {
    int xi = __builtin_bit_cast(int, x);
    int r  = __builtin_amdgcn_update_dpp(0, xi, CTRL, 0xf, 0xf, true);
    return x + __builtin_bit_cast(float, r);
}
// Full wave64 sum; valid in lane 63 (row_shr direction — verified R5).
__device__ __forceinline__ float wave_sum63(float v) {
    v = dpp_add<0x111>(v);   // row_shr:1
    v = dpp_add<0x112>(v);   // row_shr:2
    v = dpp_add<0x114>(v);   // row_shr:4
    v = dpp_add<0x118>(v);   // row_shr:8
    v = dpp_add<0x142>(v);   // row_bcast:15
    v = dpp_add<0x143>(v);   // row_bcast:31
    return v;
}
// Sum over each 16-lane row, result in ALL lanes of the row (pure full-rate DPP).
__device__ __forceinline__ float allsum16(float v) {
    v = dpp_add<0xB1>(v);    // quad_perm [1,0,3,2]  (xor1)
    v = dpp_add<0x4E>(v);    // quad_perm [2,3,0,1]  (xor2) -> quad sums
    v = dpp_add<0x124>(v);   // row_ror:4
    v = dpp_add<0x128>(v);   // row_ror:8 -> all 4 quads summed
    return v;
}

__global__ __launch_bounds__(T, 2) void caps_kernel(const float* __restrict__ x,
                                                    const float* __restrict__ w,
                                                    float* __restrict__ dout,
                                                    int probs_base) {
    const int tid  = threadIdx.x;
    const int lane = tid & 63;
    const int wid  = tid >> 6;
    const int l16  = lane & 15;
    const int quad = lane >> 4;
    const bool q0  = (quad == 0);
    const int b  = blockIdx.x >> 3;
    const int og = blockIdx.x & 7;

    __shared__ __align__(16) unsigned short xA[NCAPS][ILEN];       // 18432 B
    __shared__ __align__(16) unsigned short xaugT[10 * XT_PITCH];  // 23120 B
    __shared__ __align__(16) unsigned short Yl[OLEN][16];          // 512 B (rows 8..15 stay 0)
    __shared__ __align__(16) float Wl[OG][OLEN][ILEN];             // 4096 B
    __shared__ __align__(16) float Scmb[NWAVE][OLEN][17];          // 4352 B
    __shared__ __align__(16) unsigned short eL[OG * E_PITCH];      // 18560 B
    __shared__ float ZL[OG];

    // ---- prologue ----
    ((float4*)&Wl[0][0][0])[tid] = ((const float4*)(w + (size_t)og * OG * OLEN * ILEN))[tid];
    if (tid < 128) ((unsigned*)&Yl[0][0])[tid] = 0;

    float acc0 = 0.f, acc1 = 0.f, acc2 = 0.f, acc3 = 0.f;
    float acc4 = 0.f, acc5 = 0.f, acc6 = 0.f, acc7 = 0.f;
    const float4* xs = (const float4*)(x + (size_t)b * NCAPS * ILEN);
    #pragma unroll
    for (int p = 0; p < 5; ++p) {
        const int row = p * T + tid;
        if (row < NCAPS) {
            float4 x0 = xs[row * 2], x1 = xs[row * 2 + 1];
            acc0 += x0.x; acc1 += x0.y; acc2 += x0.z; acc3 += x0.w;
            acc4 += x1.x; acc5 += x1.y; acc6 += x1.z; acc7 += x1.w;
            unsigned h0 = f2bf_u(x0.x), h1 = f2bf_u(x0.y), h2 = f2bf_u(x0.z), h3 = f2bf_u(x0.w);
            unsigned h4 = f2bf_u(x1.x), h5 = f2bf_u(x1.y), h6 = f2bf_u(x1.z), h7 = f2bf_u(x1.w);
            *(uint4*)&xA[row][0] = make_uint4(h0 | (h1 << 16), h2 | (h3 << 16),
                                              h4 | (h5 << 16), h6 | (h7 << 16));
            xaugT[0 * XT_PITCH + row] = (unsigned short)h0;
            xaugT[1 * XT_PITCH + row] = (unsigned short)h1;
            xaugT[2 * XT_PITCH + row] = (unsigned short)h2;
            xaugT[3 * XT_PITCH + row] = (unsigned short)h3;
            xaugT[4 * XT_PITCH + row] = (unsigned short)h4;
            xaugT[5 * XT_PITCH + row] = (unsigned short)h5;
            xaugT[6 * XT_PITCH + row] = (unsigned short)h6;
            xaugT[7 * XT_PITCH + row] = (unsigned short)h7;
            xaugT[8 * XT_PITCH + row] = 0x3F80;   // ones column (z)
        }
    }
    for (int idx = tid; idx < XT_PITCH; idx += T) xaugT[9 * XT_PITCH + idx] = 0;

    // it0 column sums (fp32): wave-reduce, lane 63 writes Scmb[wid][0][0..7]
    acc0 = wave_sum63(acc0); acc1 = wave_sum63(acc1);
    acc2 = wave_sum63(acc2); acc3 = wave_sum63(acc3);
    acc4 = wave_sum63(acc4); acc5 = wave_sum63(acc5);
    acc6 = wave_sum63(acc6); acc7 = wave_sum63(acc7);
    if (lane == 63) {
        Scmb[wid][0][0] = acc0; Scmb[wid][0][1] = acc1;
        Scmb[wid][0][2] = acc2; Scmb[wid][0][3] = acc3;
        Scmb[wid][0][4] = acc4; Scmb[wid][0][5] = acc5;
        Scmb[wid][0][6] = acc6; Scmb[wid][0][7] = acc7;
    }
    __syncthreads();

    const int jr = (l16 < 9) ? l16 : 9;   // S-GEMM B row (cols >=9 read the zero row)
    const unsigned short* xTw = xaugT + jr * XT_PITCH + wid * (TPW * 16) + 4 * quad;
    const unsigned short* xAw = &xA[wid * (TPW * 16) + l16][0];
    const short8 zs = {0, 0, 0, 0, 0, 0, 0, 0};
    const f32x4  zc = {0.f, 0.f, 0.f, 0.f};

    // epilogue runs on tid<128 (o = tid>>4 in [0,8), l = tid&15)
    #pragma unroll
    for (int it = 0; it <= NITER; ++it) {
        if (it > 0) {
            // ---- compute phase ----
            short8 bL = q0 ? *(const short8*)&Yl[l16][0] : zs;
            f32x4 sacc = zc;
            #pragma unroll
            for (int tt = 0; tt < TPW; ++tt) {
                uint2 t2 = *(const uint2*)(xTw + tt * 16);
                short8 bs = s8_from(t2.x, t2.y, 0u, 0u);
                short8 aL = q0 ? *(const short8*)(xAw + tt * 128) : zs;
                f32x4 d = __builtin_amdgcn_mfma_f32_16x16x32_bf16(aL, bL, zc, 0, 0, 0);
                float e0 = __expf(d[0]), e1 = __expf(d[1]);
                float e2 = __expf(d[2]), e3 = __expf(d[3]);
                unsigned p0 = pack2(e0, e1), p1 = pack2(e2, e3);
                if (it == NITER && l16 < OG) {
                    const int n0 = wid * (TPW * 16) + tt * 16 + 4 * quad;
                    *(unsigned*)&eL[l16 * E_PITCH + n0]     = p0;
                    *(unsigned*)&eL[l16 * E_PITCH + n0 + 2] = p1;
                }
                short8 as = s8_from(p0, p1, 0u, 0u);
                sacc = __builtin_amdgcn_mfma_f32_16x16x32_bf16(as, bs, sacc, 0, 0, 0);
            }
            #pragma unroll
            for (int r = 0; r < 4; ++r) Scmb[wid][4 * quad + r][l16] = sacc[r];
            __syncthreads();
        }

        // ---- epilogue (tid < 128) ----
        if (tid < 128) {
            const int o = tid >> 4, l = tid & 15;
            float sv[9];
            if (it == 0) {
                #pragma unroll
                for (int i = 0; i < 8; ++i) {
                    float t = Scmb[0][0][i];
                    #pragma unroll
                    for (int ww = 1; ww < NWAVE; ++ww) t += Scmb[ww][0][i];
                    sv[i] = t;
                }
                sv[8] = (float)NCAPS;
            } else {
                #pragma unroll
                for (int i = 0; i < 9; ++i) {
                    float t = Scmb[0][o][i];
                    #pragma unroll
                    for (int ww = 1; ww < NWAVE; ++ww) t += Scmb[ww][o][i];
                    sv[i] = t;
                }
            }
            const float zinv = 1.0f / sv[8];
            const float* wrow = &Wl[o][l][0];
            float outl = wrow[0] * sv[0];
            #pragma unroll
            for (int i = 1; i < ILEN; ++i) outl = fmaf(wrow[i], sv[i], outl);
            outl *= zinv;

            if (it < NITER) {
                float n2 = allsum16(outl * outl);
                const float inv = 1.0f / fmaxf(sqrtf(n2), 1e-12f);
                const float oh = outl * inv;
                #pragma unroll
                for (int i = 0; i < ILEN; ++i) {
                    float yi = allsum16(wrow[i] * oh);
                    if (l == i) Yl[o][i] = (unsigned short)f2bf_u(yi);
                }
            } else {
                dout[((size_t)(b * OCAPS + og * OG)) * OLEN + tid] = outl;
                if (l == 0) ZL[o] = zinv;
            }
        }
        __syncthreads();
    }

    // ---- probs: stream eL (bf16) * zinv, coalesced float4 stores ----
    #pragma unroll
    for (int o = 0; o < OG; ++o) {
        const float zi = ZL[o];
        float* pp = dout + (size_t)probs_base + (size_t)(b * OCAPS + og * OG + o) * NCAPS;
        for (int c = tid; c < NCAPS / 4; c += T) {
            uint2 t = *(const uint2*)&eL[o * E_PITCH + 4 * c];
            float4 v;
            v.x = bf2f(t.x & 0xFFFFu) * zi;
            v.y = bf2f(t.x >> 16) * zi;
            v.z = bf2f(t.y & 0xFFFFu) * zi;
            v.w = bf2f(t.y >> 16) * zi;
            ((float4*)pp)[c] = v;
        }
    }
}

extern "C" void kernel_launch(void* const* d_in, const int* in_sizes, int n_in,
                              void* d_out, int out_size, void* d_ws, size_t ws_size,
                              hipStream_t stream) {
    const float* x = (const float*)d_in[0];
    const float* w = (const float*)d_in[1];
    float* out = (float*)d_out;
    const int Bv = in_sizes[0] / (NCAPS * ILEN);        // 64
    const int nblocks = Bv * (OCAPS / OG);              // 512
    const int probs_base = Bv * OCAPS * OLEN;           // 65536
    caps_kernel<<<dim3(nblocks), dim3(T), 0, stream>>>(x, w, out, probs_base);
}

// Round 8
// 72.329 us; speedup vs baseline: 1.0751x; 1.0751x over previous
//
#include <hip/hip_runtime.h>
#include <math.h>

// CapsuleLinear routing — MFMA formulation, round 8 = R6 skeleton + 2 fixes:
//   (1) it=0 folded into prologue (fp32 column sums, no MFMA pass)
//   (2) probs written coalesced via reuse of the dead xA/xaugT LDS pool
// logits = Xb @ Y (K=8 pad 32), S_aug = P^T @ [Xb | 1] via
// mfma_f32_16x16x32_bf16 (layouts verified R6: A[m=lane&15][k=quad*8+j],
// C/D[col=lane&15][row=quad*4+reg]).
// Grid 256 = 64 b x 4 og (16 capsules each), T=512 (8 waves), 9 n-tiles/wave.

#define NCAPS 1152
#define ILEN  8
#define OCAPS 64
#define OLEN  16
#define T     512
#define NWAVE 8
#define TPW   9          // n-tiles of 16 per wave (72 total)
#define NITER 3
#define OG    16
#define XT_PITCH 1156    // ushorts per xaugT row
#define E_PITCH  1160    // ushorts per eL row (bank stride 580%32=4)

typedef __attribute__((ext_vector_type(8))) short short8;
typedef __attribute__((ext_vector_type(4))) float f32x4;

__device__ __forceinline__ unsigned f2bf_u(float f) {   // RNE float->bf16 bits
    unsigned u = __builtin_bit_cast(unsigned, f);
    return (u + 0x7FFFu + ((u >> 16) & 1u)) >> 16;
}
__device__ __forceinline__ unsigned pack2(float a, float b) {
    return f2bf_u(a) | (f2bf_u(b) << 16);
}
__device__ __forceinline__ float bf2f(unsigned h) {
    return __builtin_bit_cast(float, h << 16);
}
__device__ __forceinline__ short8 s8_from(unsigned a, unsigned b, unsigned c, unsigned d) {
    uint4 t = make_uint4(a, b, c, d);
    return __builtin_bit_cast(short8, t);
}

template<int CTRL>
__device__ __forceinline__ float dpp_add(float x) {
    int xi = __builtin_bit_cast(int, x);
    int r  = __builtin_amdgcn_update_dpp(0, xi, CTRL, 0xf, 0xf, true);
    return x + __builtin_bit_cast(float, r);
}
// Full wave64 sum; valid in lane 63 (row_shr direction — verified R5/R7).
__device__ __forceinline__ float wave_sum63(float v) {
    v = dpp_add<0x111>(v);
    v = dpp_add<0x112>(v);
    v = dpp_add<0x114>(v);
    v = dpp_add<0x118>(v);
    v = dpp_add<0x142>(v);   // row_bcast:15
    v = dpp_add<0x143>(v);   // row_bcast:31
    return v;
}
// Sum over each 16-lane row, valid in ALL lanes of the row (verified R7).
__device__ __forceinline__ float allsum16(float v) {
    v = dpp_add<0xB1>(v);    // quad_perm xor1
    v = dpp_add<0x4E>(v);    // quad_perm xor2
    v = dpp_add<0x124>(v);   // row_ror:4
    v = dpp_add<0x128>(v);   // row_ror:8
    return v;
}

__global__ __launch_bounds__(T, 2) void caps_kernel(const float* __restrict__ x,
                                                    const float* __restrict__ w,
                                                    float* __restrict__ dout,
                                                    int probs_base) {
    const int tid  = threadIdx.x;
    const int lane = tid & 63;
    const int wid  = tid >> 6;
    const int l16  = lane & 15;
    const int quad = lane >> 4;
    const bool q0  = (quad == 0);
    const int b  = blockIdx.x >> 2;
    const int og = blockIdx.x & 3;

    // pool: xA [1152][8] (9216 ush) + xaugT [10][1156] (11560 ush) = 41552 B.
    // After the last compute pass it is reused as eL [16][E_PITCH] (37120 B).
    __shared__ __align__(16) unsigned short pool[NCAPS * ILEN + 10 * XT_PITCH];
    __shared__ __align__(16) unsigned short Yl[OLEN][16];          // 512 B
    __shared__ __align__(16) float Wl[OG][OLEN][ILEN];             // 8192 B
    __shared__ __align__(16) float Scmb[NWAVE][OLEN][17];          // 8704 B
    __shared__ float ZL[OG];
    unsigned short* xA    = pool;                  // [n][i] bf16 rows
    unsigned short* xaugT = pool + NCAPS * ILEN;   // rows j=0..7 x^T, 8=ones, 9=zeros

    // ---- prologue: stage W, stage x (two bf16 layouts), fp32 column sums ----
    ((float4*)&Wl[0][0][0])[tid] = ((const float4*)(w + (size_t)og * OG * OLEN * ILEN))[tid];

    float a0 = 0.f, a1 = 0.f, a2 = 0.f, a3 = 0.f;
    float a4 = 0.f, a5 = 0.f, a6 = 0.f, a7 = 0.f;
    const float4* xs = (const float4*)(x + (size_t)b * NCAPS * ILEN);
    #pragma unroll
    for (int p = 0; p < 3; ++p) {
        const int row = p * T + tid;
        if (row < NCAPS) {
            float4 x0 = xs[row * 2], x1 = xs[row * 2 + 1];
            a0 += x0.x; a1 += x0.y; a2 += x0.z; a3 += x0.w;
            a4 += x1.x; a5 += x1.y; a6 += x1.z; a7 += x1.w;
            unsigned h0 = f2bf_u(x0.x), h1 = f2bf_u(x0.y), h2 = f2bf_u(x0.z), h3 = f2bf_u(x0.w);
            unsigned h4 = f2bf_u(x1.x), h5 = f2bf_u(x1.y), h6 = f2bf_u(x1.z), h7 = f2bf_u(x1.w);
            *(uint4*)&xA[row * ILEN] = make_uint4(h0 | (h1 << 16), h2 | (h3 << 16),
                                                  h4 | (h5 << 16), h6 | (h7 << 16));
            xaugT[0 * XT_PITCH + row] = (unsigned short)h0;
            xaugT[1 * XT_PITCH + row] = (unsigned short)h1;
            xaugT[2 * XT_PITCH + row] = (unsigned short)h2;
            xaugT[3 * XT_PITCH + row] = (unsigned short)h3;
            xaugT[4 * XT_PITCH + row] = (unsigned short)h4;
            xaugT[5 * XT_PITCH + row] = (unsigned short)h5;
            xaugT[6 * XT_PITCH + row] = (unsigned short)h6;
            xaugT[7 * XT_PITCH + row] = (unsigned short)h7;
            xaugT[8 * XT_PITCH + row] = 0x3F80;   // ones column (z)
        }
    }
    for (int idx = tid; idx < XT_PITCH; idx += T) xaugT[9 * XT_PITCH + idx] = 0;

    // it=0 column sums (exact fp32): lane 63 of each wave -> Scmb[wid][0][0..7]
    a0 = wave_sum63(a0); a1 = wave_sum63(a1); a2 = wave_sum63(a2); a3 = wave_sum63(a3);
    a4 = wave_sum63(a4); a5 = wave_sum63(a5); a6 = wave_sum63(a6); a7 = wave_sum63(a7);
    if (lane == 63) {
        Scmb[wid][0][0] = a0; Scmb[wid][0][1] = a1;
        Scmb[wid][0][2] = a2; Scmb[wid][0][3] = a3;
        Scmb[wid][0][4] = a4; Scmb[wid][0][5] = a5;
        Scmb[wid][0][6] = a6; Scmb[wid][0][7] = a7;
    }
    __syncthreads();

    const int jr = (l16 < 9) ? l16 : 9;   // S-GEMM B row (cols >=9 read the zero row)
    const unsigned short* xTw = xaugT + jr * XT_PITCH + wid * (TPW * 16) + 4 * quad;
    const unsigned short* xAw = xA + (wid * (TPW * 16) + l16) * ILEN;
    const short8 zs = {0, 0, 0, 0, 0, 0, 0, 0};
    const f32x4  zc = {0.f, 0.f, 0.f, 0.f};

    unsigned st0[TPW], st1[TPW];   // it=3 packed e (bf16x2), registers only

    #pragma unroll
    for (int it = 0; it <= NITER; ++it) {
        if (it > 0) {
            // ---- compute phase ----
            short8 bL = q0 ? *(const short8*)&Yl[l16][0] : zs;
            f32x4 sacc = zc;
            #pragma unroll
            for (int tt = 0; tt < TPW; ++tt) {
                uint2 t2 = *(const uint2*)(xTw + tt * 16);
                short8 bs = s8_from(t2.x, t2.y, 0u, 0u);
                short8 aL = q0 ? *(const short8*)(xAw + tt * 128) : zs;
                f32x4 d = __builtin_amdgcn_mfma_f32_16x16x32_bf16(aL, bL, zc, 0, 0, 0);
                float e0 = __expf(d[0]), e1 = __expf(d[1]);
                float e2 = __expf(d[2]), e3 = __expf(d[3]);
                unsigned p0 = pack2(e0, e1), p1 = pack2(e2, e3);
                if (it == NITER) { st0[tt] = p0; st1[tt] = p1; }
                short8 as = s8_from(p0, p1, 0u, 0u);
                sacc = __builtin_amdgcn_mfma_f32_16x16x32_bf16(as, bs, sacc, 0, 0, 0);
            }
            #pragma unroll
            for (int r = 0; r < 4; ++r) Scmb[wid][4 * quad + r][l16] = sacc[r];
            __syncthreads();   // also: pool reads complete -> reusable at it==NITER
        }

        // ---- epilogue (tid < 256: o = tid>>4, l = tid&15) ----
        if (tid < 256) {
            const int o = tid >> 4, l = tid & 15;
            float sv[9];
            if (it == 0) {
                #pragma unroll
                for (int i = 0; i < 8; ++i) {
                    float t = Scmb[0][0][i];
                    #pragma unroll
                    for (int ww = 1; ww < NWAVE; ++ww) t += Scmb[ww][0][i];
                    sv[i] = t;
                }
                sv[8] = (float)NCAPS;
            } else {
                #pragma unroll
                for (int i = 0; i < 9; ++i) {
                    float t = Scmb[0][o][i];
                    #pragma unroll
                    for (int ww = 1; ww < NWAVE; ++ww) t += Scmb[ww][o][i];
                    sv[i] = t;
                }
            }
            const float zinv = 1.0f / sv[8];
            const float* wrow = &Wl[o][l][0];
            float outl = wrow[0] * sv[0];
            #pragma unroll
            for (int i = 1; i < ILEN; ++i) outl = fmaf(wrow[i], sv[i], outl);
            outl *= zinv;

            if (it < NITER) {
                float n2 = allsum16(outl * outl);
                const float inv = 1.0f / fmaxf(sqrtf(n2), 1e-12f);
                const float oh = outl * inv;
                #pragma unroll
                for (int i = 0; i < ILEN; ++i) {
                    float yi = allsum16(wrow[i] * oh);
                    if (l == i) Yl[o][i] = (unsigned short)f2bf_u(yi);
                }
            } else {
                dout[(((size_t)(b * OCAPS + og * OG + o)) << 4) + l] = outl;
                if (l == 0) ZL[o] = zinv;
            }
        }

        if (it == NITER) {
            // pool is dead: stash e into eL[l16][n] for coalesced streaming
            unsigned short* eL = pool;
            const int n0 = wid * (TPW * 16) + 4 * quad;
            #pragma unroll
            for (int tt = 0; tt < TPW; ++tt) {
                *(unsigned*)&eL[l16 * E_PITCH + n0 + tt * 16]     = st0[tt];
                *(unsigned*)&eL[l16 * E_PITCH + n0 + tt * 16 + 2] = st1[tt];
            }
        }
        __syncthreads();
    }

    // ---- probs: stream eL (bf16) * zinv, fully coalesced float4 stores ----
    {
        const unsigned short* eL = pool;
        const int o  = tid >> 5;          // 16 rows over 512 threads
        const int c0 = tid & 31;
        const float zi = ZL[o];
        float* pp = dout + (size_t)probs_base + (size_t)(b * OCAPS + og * OG + o) * NCAPS;
        #pragma unroll
        for (int j = 0; j < 9; ++j) {     // 9 x 32 = 288 float4 per row
            const int c = c0 + 32 * j;
            uint2 t = *(const uint2*)&eL[o * E_PITCH + 4 * c];
            float4 v;
            v.x = bf2f(t.x & 0xFFFFu) * zi;
            v.y = bf2f(t.x >> 16) * zi;
            v.z = bf2f(t.y & 0xFFFFu) * zi;
            v.w = bf2f(t.y >> 16) * zi;
            ((float4*)pp)[c] = v;
        }
    }
}

extern "C" void kernel_launch(void* const* d_in, const int* in_sizes, int n_in,
                              void* d_out, int out_size, void* d_ws, size_t ws_size,
                              hipStream_t stream) {
    const float* x = (const float*)d_in[0];
    const float* w = (const float*)d_in[1];
    float* out = (float*)d_out;
    const int Bv = in_sizes[0] / (NCAPS * ILEN);        // 64
    const int nblocks = Bv * (OCAPS / OG);              // 256
    const int probs_base = Bv * OCAPS * OLEN;           // 65536
    caps_kernel<<<dim3(nblocks), dim3(T), 0, stream>>>(x, w, out, probs_base);
}

// Round 9
// 71.629 us; speedup vs baseline: 1.0856x; 1.0098x over previous
//
#include <hip/hip_runtime.h>
#include <math.h>

// CapsuleLinear routing — MFMA formulation, round 9 = R8 with 12 waves/block.
// Theory: R8 (8 waves = 2/SIMD) is latency-exposed, not work-bound.
// T=768 -> 3 waves/SIMD, MFMA chain 9->6 tiles, single-round staging
// (2 rows/thread), vectorized Scmb combine (b128 broadcast reads).
// Layouts verified R6: A[m=lane&15][k=quad*8+j], C/D[col=lane&15][row=quad*4+reg].

#define NCAPS 1152
#define ILEN  8
#define OCAPS 64
#define OLEN  16
#define T     768
#define NWAVE 12
#define TPW   6          // n-tiles of 16 per wave (72 total)
#define NITER 3
#define OG    16
#define XT_PITCH 1156    // ushorts per xaugT row
#define E_PITCH  1160    // ushorts per eL row
#define SC_PITCH 20      // floats per Scmb[o][i] row (16B-aligned, bank-clean)

typedef __attribute__((ext_vector_type(8))) short short8;
typedef __attribute__((ext_vector_type(4))) float f32x4;

__device__ __forceinline__ unsigned f2bf_u(float f) {   // RNE float->bf16 bits
    unsigned u = __builtin_bit_cast(unsigned, f);
    return (u + 0x7FFFu + ((u >> 16) & 1u)) >> 16;
}
__device__ __forceinline__ unsigned pack2(float a, float b) {
    return f2bf_u(a) | (f2bf_u(b) << 16);
}
__device__ __forceinline__ float bf2f(unsigned h) {
    return __builtin_bit_cast(float, h << 16);
}
__device__ __forceinline__ short8 s8_from(unsigned a, unsigned b, unsigned c, unsigned d) {
    uint4 t = make_uint4(a, b, c, d);
    return __builtin_bit_cast(short8, t);
}

template<int CTRL>
__device__ __forceinline__ float dpp_add(float x) {
    int xi = __builtin_bit_cast(int, x);
    int r  = __builtin_amdgcn_update_dpp(0, xi, CTRL, 0xf, 0xf, true);
    return x + __builtin_bit_cast(float, r);
}
// Full wave64 sum; valid in lane 63 (row_shr direction — verified R5/R7).
__device__ __forceinline__ float wave_sum63(float v) {
    v = dpp_add<0x111>(v);
    v = dpp_add<0x112>(v);
    v = dpp_add<0x114>(v);
    v = dpp_add<0x118>(v);
    v = dpp_add<0x142>(v);   // row_bcast:15
    v = dpp_add<0x143>(v);   // row_bcast:31
    return v;
}
// Sum over each 16-lane row, valid in ALL lanes of the row (verified R7).
__device__ __forceinline__ float allsum16(float v) {
    v = dpp_add<0xB1>(v);    // quad_perm xor1
    v = dpp_add<0x4E>(v);    // quad_perm xor2
    v = dpp_add<0x124>(v);   // row_ror:4
    v = dpp_add<0x128>(v);   // row_ror:8
    return v;
}

__global__ __launch_bounds__(T, 3) void caps_kernel(const float* __restrict__ x,
                                                    const float* __restrict__ w,
                                                    float* __restrict__ dout,
                                                    int probs_base) {
    const int tid  = threadIdx.x;
    const int lane = tid & 63;
    const int wid  = tid >> 6;
    const int l16  = lane & 15;
    const int quad = lane >> 4;
    const bool q0  = (quad == 0);
    const int b  = blockIdx.x >> 2;
    const int og = blockIdx.x & 3;

    // pool: xA [1152][8] + xaugT [10][1156] = 41552 B; reused as eL [16][E_PITCH] (37120 B)
    __shared__ __align__(16) unsigned short pool[NCAPS * ILEN + 10 * XT_PITCH];
    __shared__ __align__(16) unsigned short Yl[OLEN][16];           // 512 B
    __shared__ __align__(16) float Wl[OG][OLEN][ILEN];              // 8192 B
    __shared__ __align__(16) float Scmb[OLEN][OLEN][SC_PITCH];     // [o][i][wave] 20480 B
    __shared__ float ZL[OG];
    unsigned short* xA    = pool;                  // [n][i] bf16 rows
    unsigned short* xaugT = pool + NCAPS * ILEN;   // rows j=0..7 x^T, 8=ones, 9=zeros

    // ---- prologue: W, Yl init, single-round x staging (2 rows/thread) ----
    if (tid < 512)
        ((float4*)&Wl[0][0][0])[tid] = ((const float4*)(w + (size_t)og * OG * OLEN * ILEN))[tid];
    if (tid < 128) ((unsigned*)&Yl[0][0])[tid] = 0;

    float a0 = 0.f, a1 = 0.f, a2 = 0.f, a3 = 0.f;
    float a4 = 0.f, a5 = 0.f, a6 = 0.f, a7 = 0.f;
    if (tid < NCAPS / 2) {
        const float4* xs = (const float4*)(x + (size_t)b * NCAPS * ILEN);
        float4 x0 = xs[4 * tid], x1 = xs[4 * tid + 1];
        float4 x2 = xs[4 * tid + 2], x3 = xs[4 * tid + 3];
        a0 = x0.x + x2.x; a1 = x0.y + x2.y; a2 = x0.z + x2.z; a3 = x0.w + x2.w;
        a4 = x1.x + x3.x; a5 = x1.y + x3.y; a6 = x1.z + x3.z; a7 = x1.w + x3.w;
        unsigned g0 = f2bf_u(x0.x), g1 = f2bf_u(x0.y), g2 = f2bf_u(x0.z), g3 = f2bf_u(x0.w);
        unsigned g4 = f2bf_u(x1.x), g5 = f2bf_u(x1.y), g6 = f2bf_u(x1.z), g7 = f2bf_u(x1.w);
        unsigned h0 = f2bf_u(x2.x), h1 = f2bf_u(x2.y), h2 = f2bf_u(x2.z), h3 = f2bf_u(x2.w);
        unsigned h4 = f2bf_u(x3.x), h5 = f2bf_u(x3.y), h6 = f2bf_u(x3.z), h7 = f2bf_u(x3.w);
        const int r0 = 2 * tid;
        *(uint4*)&xA[r0 * ILEN]       = make_uint4(g0 | (g1 << 16), g2 | (g3 << 16),
                                                   g4 | (g5 << 16), g6 | (g7 << 16));
        *(uint4*)&xA[(r0 + 1) * ILEN] = make_uint4(h0 | (h1 << 16), h2 | (h3 << 16),
                                                   h4 | (h5 << 16), h6 | (h7 << 16));
        // transpose: one u32 covers rows (r0, r0+1) for column j
        *(unsigned*)&xaugT[0 * XT_PITCH + r0] = g0 | (h0 << 16);
        *(unsigned*)&xaugT[1 * XT_PITCH + r0] = g1 | (h1 << 16);
        *(unsigned*)&xaugT[2 * XT_PITCH + r0] = g2 | (h2 << 16);
        *(unsigned*)&xaugT[3 * XT_PITCH + r0] = g3 | (h3 << 16);
        *(unsigned*)&xaugT[4 * XT_PITCH + r0] = g4 | (h4 << 16);
        *(unsigned*)&xaugT[5 * XT_PITCH + r0] = g5 | (h5 << 16);
        *(unsigned*)&xaugT[6 * XT_PITCH + r0] = g6 | (h6 << 16);
        *(unsigned*)&xaugT[7 * XT_PITCH + r0] = g7 | (h7 << 16);
        *(unsigned*)&xaugT[8 * XT_PITCH + r0] = 0x3F803F80u;   // ones (z column)
    }
    for (int idx = tid; idx < XT_PITCH; idx += T) xaugT[9 * XT_PITCH + idx] = 0;

    // it=0 column sums (exact fp32): lane 63 of each wave -> Scmb[0][i][wid]
    a0 = wave_sum63(a0); a1 = wave_sum63(a1); a2 = wave_sum63(a2); a3 = wave_sum63(a3);
    a4 = wave_sum63(a4); a5 = wave_sum63(a5); a6 = wave_sum63(a6); a7 = wave_sum63(a7);
    if (lane == 63) {
        Scmb[0][0][wid] = a0; Scmb[0][1][wid] = a1;
        Scmb[0][2][wid] = a2; Scmb[0][3][wid] = a3;
        Scmb[0][4][wid] = a4; Scmb[0][5][wid] = a5;
        Scmb[0][6][wid] = a6; Scmb[0][7][wid] = a7;
    }
    __syncthreads();

    const int jr = (l16 < 9) ? l16 : 9;   // S-GEMM B row (cols >=9 read the zero row)
    const unsigned short* xTw = xaugT + jr * XT_PITCH + wid * (TPW * 16) + 4 * quad;
    const unsigned short* xAw = xA + (wid * (TPW * 16) + l16) * ILEN;
    const short8 zs = {0, 0, 0, 0, 0, 0, 0, 0};
    const f32x4  zc = {0.f, 0.f, 0.f, 0.f};

    unsigned st0[TPW], st1[TPW];   // it=3 packed e (bf16x2), registers only

    #pragma unroll
    for (int it = 0; it <= NITER; ++it) {
        if (it > 0) {
            // ---- compute phase (6-tile chain per wave) ----
            short8 bL = q0 ? *(const short8*)&Yl[l16][0] : zs;
            f32x4 sacc = zc;
            #pragma unroll
            for (int tt = 0; tt < TPW; ++tt) {
                uint2 t2 = *(const uint2*)(xTw + tt * 16);
                short8 bs = s8_from(t2.x, t2.y, 0u, 0u);
                short8 aL = q0 ? *(const short8*)(xAw + tt * 128) : zs;
                f32x4 d = __builtin_amdgcn_mfma_f32_16x16x32_bf16(aL, bL, zc, 0, 0, 0);
                float e0 = __expf(d[0]), e1 = __expf(d[1]);
                float e2 = __expf(d[2]), e3 = __expf(d[3]);
                unsigned p0 = pack2(e0, e1), p1 = pack2(e2, e3);
                if (it == NITER) { st0[tt] = p0; st1[tt] = p1; }
                short8 as = s8_from(p0, p1, 0u, 0u);
                sacc = __builtin_amdgcn_mfma_f32_16x16x32_bf16(as, bs, sacc, 0, 0, 0);
            }
            #pragma unroll
            for (int r = 0; r < 4; ++r) Scmb[4 * quad + r][l16][wid] = sacc[r];
            __syncthreads();
        }

        // ---- epilogue (tid < 256: o = tid>>4, l = tid&15) ----
        if (tid < 256) {
            const int o = tid >> 4, l = tid & 15;
            const int oi = (it == 0) ? 0 : o;
            float sv[9];
            #pragma unroll
            for (int i = 0; i < 9; ++i) {
                // 12 wave-partials, vectorized broadcast reads
                float4 v0 = *(const float4*)&Scmb[oi][i][0];
                float4 v1 = *(const float4*)&Scmb[oi][i][4];
                float4 v2 = *(const float4*)&Scmb[oi][i][8];
                sv[i] = ((v0.x + v0.y) + (v0.z + v0.w))
                      + ((v1.x + v1.y) + (v1.z + v1.w))
                      + ((v2.x + v2.y) + (v2.z + v2.w));
            }
            if (it == 0) sv[8] = (float)NCAPS;
            const float zinv = 1.0f / sv[8];
            const float* wrow = &Wl[o][l][0];
            float outl = wrow[0] * sv[0];
            #pragma unroll
            for (int i = 1; i < ILEN; ++i) outl = fmaf(wrow[i], sv[i], outl);
            outl *= zinv;

            if (it < NITER) {
                float n2 = allsum16(outl * outl);
                const float inv = 1.0f / fmaxf(sqrtf(n2), 1e-12f);
                const float oh = outl * inv;
                #pragma unroll
                for (int i = 0; i < ILEN; ++i) {
                    float yi = allsum16(wrow[i] * oh);
                    if (l == i) Yl[o][i] = (unsigned short)f2bf_u(yi);
                }
            } else {
                dout[(((size_t)(b * OCAPS + og * OG + o)) << 4) + l] = outl;
                if (l == 0) ZL[o] = zinv;
            }
        }

        if (it == NITER) {
            // pool is dead: stash e into eL[l16][n] for coalesced streaming
            unsigned short* eL = pool;
            const int n0 = wid * (TPW * 16) + 4 * quad;
            #pragma unroll
            for (int tt = 0; tt < TPW; ++tt) {
                *(unsigned*)&eL[l16 * E_PITCH + n0 + tt * 16]     = st0[tt];
                *(unsigned*)&eL[l16 * E_PITCH + n0 + tt * 16 + 2] = st1[tt];
            }
        }
        __syncthreads();
    }

    // ---- probs: stream eL (bf16) * zinv, coalesced float4 stores ----
    {
        const unsigned short* eL = pool;
        float* pbase = dout + (size_t)probs_base + (size_t)(b * OCAPS + og * OG) * NCAPS;
        #pragma unroll
        for (int j = 0; j < 6; ++j) {
            const int f = tid + j * T;        // 0 .. 4607
            const int o = f / (NCAPS / 4);
            const int c = f - o * (NCAPS / 4);
            const float zi = ZL[o];
            uint2 t = *(const uint2*)&eL[o * E_PITCH + 4 * c];
            float4 v;
            v.x = bf2f(t.x & 0xFFFFu) * zi;
            v.y = bf2f(t.x >> 16) * zi;
            v.z = bf2f(t.y & 0xFFFFu) * zi;
            v.w = bf2f(t.y >> 16) * zi;
            ((float4*)(pbase + (size_t)o * NCAPS))[c] = v;
        }
    }
}

extern "C" void kernel_launch(void* const* d_in, const int* in_sizes, int n_in,
                              void* d_out, int out_size, void* d_ws, size_t ws_size,
                              hipStream_t stream) {
    const float* x = (const float*)d_in[0];
    const float* w = (const float*)d_in[1];
    float* out = (float*)d_out;
    const int Bv = in_sizes[0] / (NCAPS * ILEN);        // 64
    const int nblocks = Bv * (OCAPS / OG);              // 256
    const int probs_base = Bv * OCAPS * OLEN;           // 65536
    caps_kernel<<<dim3(nblocks), dim3(T), 0, stream>>>(x, w, out, probs_base);
}